// Round 1
// 363.028 us; speedup vs baseline: 1.0014x; 1.0014x over previous
//
#include <hip/hip_runtime.h>

// LRU forward, MI355X/gfx950.
// Pipeline: prep (lambda/gamma/Bcat/Ccat/bf16-inputs) -> GEMM1 (Bu) ->
// chunked scan (32 chunks of 128, carry fix-up, in-place hs) -> GEMM2 (+skip).
// R2: 1D-grid XCD-compact swizzle. R3: double-buffered 128^2 (363us, 613TF).
// R4: 256^2 tile, 8 waves, BK=32, 4-deep LDS ring with COUNTED vmcnt across
// RAW s_barrier (T3+T4): stage of tile kt+3 issues before compute of tile kt,
// drain is s_waitcnt vmcnt(8) (2 tiles stay in flight across the barrier).
// __syncthreads was the ceiling: it drains vmcnt(0) at every barrier.

typedef __bf16 bf16x8 __attribute__((ext_vector_type(8)));
typedef float floatx4 __attribute__((ext_vector_type(4)));

__device__ __forceinline__ unsigned short f2bf(float f) {
  unsigned u = __float_as_uint(f);
  u += 0x7fffu + ((u >> 16) & 1u);   // RNE; inputs are finite
  return (unsigned short)(u >> 16);
}
__device__ __forceinline__ float bf2f(unsigned short s) {
  return __uint_as_float(((unsigned)s) << 16);
}

// ---------------- prep kernels ----------------

__global__ void prep_params(const float* __restrict__ nu_log,
                            const float* __restrict__ theta_log,
                            float* __restrict__ lam,    // [2048] re|im
                            float* __restrict__ lamL,   // [2048] lambda^128 re|im
                            float* __restrict__ gamma)  // [1024]
{
  int h = blockIdx.x * 256 + threadIdx.x;   // exactly 1024
  float nu = expf(nu_log[h]);
  float th = expf(theta_log[h]);
  float r = expf(-nu);
  lam[h]        = r * cosf(th);
  lam[1024 + h] = r * sinf(th);
  float rL = expf(-128.0f * nu);
  lamL[h]        = rL * cosf(128.0f * th);
  lamL[1024 + h] = rL * sinf(128.0f * th);
  gamma[h] = sqrtf(1.0f - expf(-2.0f * nu) + 1e-5f);
}

__global__ void prep_B(const float* __restrict__ B_re, const float* __restrict__ B_im,
                       const float* __restrict__ gamma, unsigned short* __restrict__ Bcat)
{
  int tid = blockIdx.x * 256 + threadIdx.x;  // 2048*1024
  int n = tid >> 10;
  int d = tid & 1023;
  int h = n & 1023;
  float v = (n < 1024 ? B_re[h * 1024 + d] : B_im[h * 1024 + d]) * gamma[h];
  Bcat[tid] = f2bf(v);
}

__global__ void prep_C(const float* __restrict__ C_re, const float* __restrict__ C_im,
                       unsigned short* __restrict__ Ccat)
{
  int tid = blockIdx.x * 256 + threadIdx.x;  // 1024*2048
  int d = tid >> 11;
  int k = tid & 2047;
  float v = (k < 1024) ? C_re[d * 1024 + k] : -C_im[d * 1024 + (k - 1024)];
  Ccat[tid] = f2bf(v);
}

__global__ void conv_inputs(const float* __restrict__ in, unsigned short* __restrict__ outb)
{
  int tid = blockIdx.x * 256 + threadIdx.x;  // 16.7M/4
  float4 v = ((const float4*)in)[tid];
  unsigned lo = (unsigned)f2bf(v.x) | ((unsigned)f2bf(v.y) << 16);
  unsigned hi = (unsigned)f2bf(v.z) | ((unsigned)f2bf(v.w) << 16);
  ((uint2*)outb)[tid] = make_uint2(lo, hi);
}

// ---------------- GEMM (A: [M,K] k-contig, Bt: [N,K] k-contig) ----------------
// 256x256 tile, BK=32, 8 waves (2x4), each wave computes 128x64 via 8x4
// 16x16x32 fragments (32 MFMA / wave / K-tile).
// LDS: 4-deep ring of (16KB A + 16KB B) K-tile buffers = 128 KiB total,
// 1 block/CU, 8 waves/CU. Stage of tile kt+3 issues at top of iteration kt
// (its buffer's reads completed before the PREVIOUS barrier); drain is a
// counted s_waitcnt vmcnt(8) + raw s_barrier (tiles kt+2, kt+3 remain in
// flight across the barrier). Tail peeled with vmcnt(4)/vmcnt(0).
// LDS swizzle (measured conflict-free): row r (64B) holds its four 16B
// k-chunks at position p storing logical chunk p ^ ((r>>1)&3); keeps
// global_load_lds lane-contiguity (dest = wave base + lane*16).
// XCD-compact swizzle: xcd = id&7 owns m-tiles [xcd*8, xcd*8+8) x all
// n-tiles, m-fastest (id%8 -> XCD mapping confirmed in R2).

#define GLDS(gp, lp) __builtin_amdgcn_global_load_lds(                        \
      (const __attribute__((address_space(1))) void*)(gp),                    \
      (__attribute__((address_space(3))) void*)(lp), 16, 0, 0)

#define STAGE(kt, buf) do {                                                   \
    const int _ko = (kt) * 32;                                                \
    GLDS(gA0 + _ko, &As[(buf)][lofs0]);                                       \
    GLDS(gA1 + _ko, &As[(buf)][lofs1]);                                       \
    GLDS(gB0 + _ko, &Bs[(buf)][lofs0]);                                       \
    GLDS(gB1 + _ko, &Bs[(buf)][lofs1]);                                       \
  } while (0)

#define BODY(buf) do {                                                        \
    bf16x8 af[8], bf[4];                                                      \
    _Pragma("unroll")                                                         \
    for (int i = 0; i < 8; ++i) {                                             \
      const int r = wm * 128 + i * 16 + lm;                                   \
      af[i] = *reinterpret_cast<const bf16x8*>(                               \
          &As[(buf)][r * 32 + (q ^ ((r >> 1) & 3)) * 8]);                     \
    }                                                                         \
    _Pragma("unroll")                                                         \
    for (int j = 0; j < 4; ++j) {                                             \
      const int r = wn * 64 + j * 16 + lm;                                    \
      bf[j] = *reinterpret_cast<const bf16x8*>(                               \
          &Bs[(buf)][r * 32 + (q ^ ((r >> 1) & 3)) * 8]);                     \
    }                                                                         \
    __builtin_amdgcn_s_setprio(1);                                            \
    _Pragma("unroll")                                                         \
    for (int i = 0; i < 8; ++i)                                               \
      _Pragma("unroll")                                                       \
      for (int j = 0; j < 4; ++j)                                             \
        acc[i][j] = __builtin_amdgcn_mfma_f32_16x16x32_bf16(                  \
            af[i], bf[j], acc[i][j], 0, 0, 0);                                \
    __builtin_amdgcn_s_setprio(0);                                            \
  } while (0)

#define RING_SYNC(vm) do {                                                    \
    __builtin_amdgcn_sched_barrier(0);                                        \
    asm volatile("s_waitcnt vmcnt(" #vm ")" ::: "memory");                    \
    __builtin_amdgcn_s_barrier();                                             \
    asm volatile("" ::: "memory");                                            \
  } while (0)

template <int EPI>
__global__ __launch_bounds__(512, 2) void gemm256_kernel(
    const unsigned short* __restrict__ A,
    const unsigned short* __restrict__ Bt,
    void* __restrict__ Cout,
    int M, int N, int K,
    const float* __restrict__ skip_in,
    const float* __restrict__ skip_w)
{
  __shared__ __align__(16) unsigned short As[4][256 * 32];
  __shared__ __align__(16) unsigned short Bs[4][256 * 32];

  const int tid  = threadIdx.x;
  const int lane = tid & 63;
  const int wave = tid >> 6;   // 0..7
  const int wm = wave >> 2;    // 0..1 (m half)
  const int wn = wave & 3;     // 0..3 (n quarter)

  // XCD-compact tile assignment (M/256 == 64 for both GEMMs: 8 XCDs x 8 m-tiles)
  const int flat    = blockIdx.x;
  const int xcd     = flat & 7;
  const int local   = flat >> 3;
  const int m_tile  = xcd * 8 + (local & 7);
  const int n_tile  = local >> 3;
  const int m0 = m_tile * 256;
  const int n0 = n_tile * 256;

  const int ldr = lane >> 2;   // 0..15: row within a 16-row staging group
  const int pos = lane & 3;    // 16B chunk position within the 64B row
  const int lm  = lane & 15;   // fragment row (A: m, B: n)
  const int q   = lane >> 4;   // fragment k-chunk (k = q*8 + j)

  // Per-thread staging geometry (two rows per thread; 8 waves x 32 rows = 256)
  const int r0 = wave * 32 + ldr;
  const int r1 = r0 + 16;
  const int ca0 = pos ^ ((r0 >> 1) & 3);
  const int ca1 = pos ^ ((r1 >> 1) & 3);

  const unsigned short* gA0 = A  + (size_t)(m0 + r0) * K + ca0 * 8;
  const unsigned short* gA1 = A  + (size_t)(m0 + r1) * K + ca1 * 8;
  const unsigned short* gB0 = Bt + (size_t)(n0 + r0) * K + ca0 * 8;
  const unsigned short* gB1 = Bt + (size_t)(n0 + r1) * K + ca1 * 8;
  const int lofs0 = r0 * 32 + pos * 8;
  const int lofs1 = r1 * 32 + pos * 8;

  floatx4 acc[8][4];
#pragma unroll
  for (int i = 0; i < 8; ++i)
#pragma unroll
    for (int j = 0; j < 4; ++j)
      acc[i][j] = (floatx4){0.f, 0.f, 0.f, 0.f};

  const int KT = K >> 5;   // 32 or 64 K-tiles; KT >= 4 assumed

  // Prologue: prefetch tiles 0..2 into ring slots 0..2 (12 loads/thread),
  // wait for tile 0 only (8 loads = tiles 1,2 stay in flight).
  STAGE(0, 0);
  STAGE(1, 1);
  STAGE(2, 2);
  asm volatile("s_waitcnt vmcnt(8)" ::: "memory");
  __builtin_amdgcn_s_barrier();
  asm volatile("" ::: "memory");

  // Steady state: buffer (kt+3)&3 last held tile kt-1, whose ds_reads all
  // completed before the previous barrier -> WAR-safe to restage now.
  // vmcnt(8) at the bottom guarantees tile kt+1 has landed (tiles kt+2 and
  // kt+3 remain outstanding across the barrier).
  for (int kt = 0; kt + 3 < KT; ++kt) {
    STAGE(kt + 3, (kt + 3) & 3);
    BODY(kt & 3);
    RING_SYNC(8);
  }
  BODY((KT - 3) & 3);
  RING_SYNC(4);            // only tile KT-1 (4 loads) may remain in flight
  BODY((KT - 2) & 3);
  RING_SYNC(0);            // drain last tile
  BODY((KT - 1) & 3);

  // Epilogue. C/D layout: col = lane&15, row = (lane>>4)*4 + reg.
#pragma unroll
  for (int i = 0; i < 8; ++i) {
#pragma unroll
    for (int j = 0; j < 4; ++j) {
      const int row0 = m0 + wm * 128 + i * 16 + q * 4;
      const int col  = n0 + wn * 64 + j * 16 + lm;
#pragma unroll
      for (int r = 0; r < 4; ++r) {
        const size_t idx = (size_t)(row0 + r) * N + col;
        if (EPI == 0) {
          ((unsigned short*)Cout)[idx] = f2bf(acc[i][j][r]);
        } else {
          ((float*)Cout)[idx] = acc[i][j][r] + skip_in[idx] * skip_w[col];
        }
      }
    }
  }
}

// ---------------- chunked scan over T ----------------
// Bu layout: [(b*4096 + t) * 2048 + h] re-plane (h<1024), +1024 im-plane.
// tid = b*32768 + c*1024 + h  (B=4, C=32 chunks of L=128, H=1024)

__global__ void scan_finals(const unsigned short* __restrict__ Bu,
                            const float* __restrict__ lam,
                            float2* __restrict__ finals)
{
  int tid = blockIdx.x * 256 + threadIdx.x;
  int h = tid & 1023, c = (tid >> 10) & 31, b = tid >> 15;
  float lre = lam[h], lim = lam[1024 + h];
  const unsigned short* p = Bu + ((size_t)(b * 4096 + c * 128) * 2048) + h;
  float yre = 0.f, yim = 0.f;
#pragma unroll 4
  for (int t = 0; t < 128; ++t) {
    float ure = bf2f(p[0]);
    float uim = bf2f(p[1024]);
    float nre = fmaf(lre, yre, fmaf(-lim, yim, ure));
    float nim = fmaf(lre, yim, fmaf(lim, yre, uim));
    yre = nre; yim = nim;
    p += 2048;
  }
  finals[tid] = make_float2(yre, yim);
}

__global__ void scan_carries(const float2* __restrict__ finals,
                             const float* __restrict__ lamL,
                             float2* __restrict__ carry)
{
  int tid = blockIdx.x * 256 + threadIdx.x;  // 4096 = B*H
  int h = tid & 1023, b = tid >> 10;
  float Lre = lamL[h], Lim = lamL[1024 + h];
  float Hre = 0.f, Him = 0.f;
  for (int c = 0; c < 32; ++c) {
    size_t i = ((size_t)(b * 32 + c) << 10) + h;
    carry[i] = make_float2(Hre, Him);   // carry INTO chunk c (H_{c-1})
    float2 f = finals[i];
    float nre = fmaf(Lre, Hre, fmaf(-Lim, Him, f.x));
    float nim = fmaf(Lre, Him, fmaf(Lim, Hre, f.y));
    Hre = nre; Him = nim;
  }
}

__global__ void scan_apply(const float* __restrict__ lam,
                           const float2* __restrict__ carry,
                           unsigned short* __restrict__ Bu)  // in-place -> hs
{
  int tid = blockIdx.x * 256 + threadIdx.x;
  int h = tid & 1023, c = (tid >> 10) & 31, b = tid >> 15;
  float lre = lam[h], lim = lam[1024 + h];
  float2 cv = carry[tid];
  float yre = cv.x, yim = cv.y;
  unsigned short* p = Bu + ((size_t)(b * 4096 + c * 128) * 2048) + h;
#pragma unroll 4
  for (int t = 0; t < 128; ++t) {
    float ure = bf2f(p[0]);
    float uim = bf2f(p[1024]);
    float nre = fmaf(lre, yre, fmaf(-lim, yim, ure));
    float nim = fmaf(lre, yim, fmaf(lim, yre, uim));
    yre = nre; yim = nim;
    p[0]    = f2bf(yre);
    p[1024] = f2bf(yim);
    p += 2048;
  }
}

// ---------------- launch ----------------

extern "C" void kernel_launch(void* const* d_in, const int* in_sizes, int n_in,
                              void* d_out, int out_size, void* d_ws, size_t ws_size,
                              hipStream_t stream)
{
  const float* inputs    = (const float*)d_in[0];
  const float* nu_log    = (const float*)d_in[1];
  const float* theta_log = (const float*)d_in[2];
  const float* B_re      = (const float*)d_in[3];
  const float* B_im      = (const float*)d_in[4];
  const float* C_re      = (const float*)d_in[5];
  const float* C_im      = (const float*)d_in[6];
  const float* D_skip    = (const float*)d_in[7];
  float* out = (float*)d_out;

  char* ws = (char*)d_ws;
  float* lam   = (float*)ws;            // 2048 f32
  float* lamL  = lam + 2048;            // 2048 f32
  float* gamma = lamL + 2048;           // 1024 f32
  unsigned short* inp_bf = (unsigned short*)(ws + (1 << 16));       // 16384x1024 bf16
  unsigned short* Bcat   = inp_bf + (size_t)16384 * 1024;           // 2048x1024
  unsigned short* Ccat   = Bcat   + (size_t)2048 * 1024;            // 1024x2048
  unsigned short* Bu     = Ccat   + (size_t)1024 * 2048;            // 16384x2048 (re|im), becomes hs in place
  float2* finals = (float2*)(Bu + (size_t)16384 * 2048);            // 131072
  float2* carry  = finals + 131072;                                 // 131072
  // total ws use ~111 MB

  prep_params<<<4,    256, 0, stream>>>(nu_log, theta_log, lam, lamL, gamma);
  prep_B     <<<8192, 256, 0, stream>>>(B_re, B_im, gamma, Bcat);
  prep_C     <<<8192, 256, 0, stream>>>(C_re, C_im, Ccat);
  conv_inputs<<<16384,256, 0, stream>>>(inputs, inp_bf);

  // GEMM1: Bu[bt, n] = inputs @ Bcat^T   (M=16384, N=2048, K=1024) -> 64x8 tiles
  gemm256_kernel<0><<<512, 512, 0, stream>>>(
      inp_bf, Bcat, Bu, 16384, 2048, 1024, nullptr, nullptr);

  scan_finals <<<512, 256, 0, stream>>>(Bu, lam, finals);
  scan_carries<<<16,  256, 0, stream>>>(finals, lamL, carry);
  scan_apply  <<<512, 256, 0, stream>>>(lam, carry, Bu);   // Bu -> hs in place

  // GEMM2: out[bt, d] = hs @ Ccat^T + inputs * D_skip  (M=16384, N=1024, K=2048) -> 64x4 tiles
  gemm256_kernel<1><<<256, 512, 0, stream>>>(
      Bu, Ccat, out, 16384, 1024, 2048, inputs, D_skip);
}

// Round 2
// 330.115 us; speedup vs baseline: 1.1013x; 1.0997x over previous
//
#include <hip/hip_runtime.h>

// LRU forward, MI355X/gfx950.
// Pipeline: prep (lambda/gamma/Bcat/Ccat/bf16-inputs) -> GEMM1 (Bu) ->
// chunked scan (32 chunks of 128, carry fix-up, in-place hs) -> GEMM2 (+skip).
// R2: XCD-compact swizzle. R3: dbuf 128^2 (613TF). R4: 256^2, 8 waves, BK=32,
// 4-deep LDS ring, counted vmcnt(8) across raw s_barrier (692TF, MfmaUtil 27%).
// R5: fine 8-phase pacing (m201/T3 mechanism): each K-tile split into two
// {ds_read subtile + 2 global_load_lds -> barrier -> setprio+16 MFMA -> barrier}
// phases. R4's coarse {12 reads -> 32 MFMA -> 1 barrier} body was the gap:
// counted vmcnt without fine interleave is ~null (m196); double-barrier pacing
// creates the wave role-split that setprio arbitrates (m218b).

typedef __bf16 bf16x8 __attribute__((ext_vector_type(8)));
typedef float floatx4 __attribute__((ext_vector_type(4)));

__device__ __forceinline__ unsigned short f2bf(float f) {
  unsigned u = __float_as_uint(f);
  u += 0x7fffu + ((u >> 16) & 1u);   // RNE; inputs are finite
  return (unsigned short)(u >> 16);
}
__device__ __forceinline__ float bf2f(unsigned short s) {
  return __uint_as_float(((unsigned)s) << 16);
}

// ---------------- prep kernels ----------------

__global__ void prep_params(const float* __restrict__ nu_log,
                            const float* __restrict__ theta_log,
                            float* __restrict__ lam,    // [2048] re|im
                            float* __restrict__ lamL,   // [2048] lambda^128 re|im
                            float* __restrict__ gamma)  // [1024]
{
  int h = blockIdx.x * 256 + threadIdx.x;   // exactly 1024
  float nu = expf(nu_log[h]);
  float th = expf(theta_log[h]);
  float r = expf(-nu);
  lam[h]        = r * cosf(th);
  lam[1024 + h] = r * sinf(th);
  float rL = expf(-128.0f * nu);
  lamL[h]        = rL * cosf(128.0f * th);
  lamL[1024 + h] = rL * sinf(128.0f * th);
  gamma[h] = sqrtf(1.0f - expf(-2.0f * nu) + 1e-5f);
}

__global__ void prep_B(const float* __restrict__ B_re, const float* __restrict__ B_im,
                       const float* __restrict__ gamma, unsigned short* __restrict__ Bcat)
{
  int tid = blockIdx.x * 256 + threadIdx.x;  // 2048*1024
  int n = tid >> 10;
  int d = tid & 1023;
  int h = n & 1023;
  float v = (n < 1024 ? B_re[h * 1024 + d] : B_im[h * 1024 + d]) * gamma[h];
  Bcat[tid] = f2bf(v);
}

__global__ void prep_C(const float* __restrict__ C_re, const float* __restrict__ C_im,
                       unsigned short* __restrict__ Ccat)
{
  int tid = blockIdx.x * 256 + threadIdx.x;  // 1024*2048
  int d = tid >> 11;
  int k = tid & 2047;
  float v = (k < 1024) ? C_re[d * 1024 + k] : -C_im[d * 1024 + (k - 1024)];
  Ccat[tid] = f2bf(v);
}

__global__ void conv_inputs(const float* __restrict__ in, unsigned short* __restrict__ outb)
{
  int tid = blockIdx.x * 256 + threadIdx.x;  // 16.7M/4
  float4 v = ((const float4*)in)[tid];
  unsigned lo = (unsigned)f2bf(v.x) | ((unsigned)f2bf(v.y) << 16);
  unsigned hi = (unsigned)f2bf(v.z) | ((unsigned)f2bf(v.w) << 16);
  ((uint2*)outb)[tid] = make_uint2(lo, hi);
}

// ---------------- GEMM (A: [M,K] k-contig, Bt: [N,K] k-contig) ----------------
// 256x256 tile, BK=32, 8 waves (2x4), per-wave 128x64 out via 8x4 16x16x32
// fragments (32 MFMA / wave / K-tile, split into two 16-MFMA phases).
// LDS: 4-deep ring of (16KB A + 16KB B) = 128 KiB, 1 block/CU, 8 waves/CU.
// Per K-tile kt (buf kt&3), staging tile kt+3 into buf (kt+3)&3:
//   phase A: ds_read bf[0..3]+af[0..3] (8 b128), GLDS A-pair, bar,
//            setprio+16 MFMA, bar.
//   phase B: ds_read af[4..7] (4 b128), GLDS B-pair, vmcnt(8), bar,
//            setprio+16 MFMA, bar.
// vmcnt(8) leaves tiles kt+2,kt+3 (8 loads) in flight across the barrier;
// tile kt+1 (needed next) was issued 2 K-tiles ago. Tail peeled vmcnt(4)/(0).
// WAR safety: buffer (kt+3)&3 last held tile kt-1 whose ds_reads drained
// before the previous K-tile's trailing barrier.
// LDS swizzle (measured conflict-free, R4): row r (64B) holds its four 16B
// k-chunks at position p storing logical chunk p ^ ((r>>1)&3).
// XCD-compact swizzle: xcd=id&7 owns m-tiles [xcd*8, xcd*8+8), m-fastest.

#define GLDS(gp, lp) __builtin_amdgcn_global_load_lds(                        \
      (const __attribute__((address_space(1))) void*)(gp),                    \
      (__attribute__((address_space(3))) void*)(lp), 16, 0, 0)

#define STAGE(kt, buf) do {                                                   \
    const int _ko = (kt) * 32;                                                \
    GLDS(gA0 + _ko, &As[(buf)][lofs0]);                                       \
    GLDS(gA1 + _ko, &As[(buf)][lofs1]);                                       \
    GLDS(gB0 + _ko, &Bs[(buf)][lofs0]);                                       \
    GLDS(gB1 + _ko, &Bs[(buf)][lofs1]);                                       \
  } while (0)

#define READ_B(buf) do {                                                      \
    _Pragma("unroll")                                                         \
    for (int j = 0; j < 4; ++j) {                                             \
      const int r = wn * 64 + j * 16 + lm;                                    \
      bfr[j] = *reinterpret_cast<const bf16x8*>(                              \
          &Bs[(buf)][r * 32 + (q ^ ((r >> 1) & 3)) * 8]);                     \
    }                                                                         \
  } while (0)

#define READ_A(buf, i0) do {                                                  \
    _Pragma("unroll")                                                         \
    for (int i = 0; i < 4; ++i) {                                             \
      const int r = wm * 128 + ((i0) + i) * 16 + lm;                          \
      afr[i] = *reinterpret_cast<const bf16x8*>(                              \
          &As[(buf)][r * 32 + (q ^ ((r >> 1) & 3)) * 8]);                     \
    }                                                                         \
  } while (0)

#define MFMA16(i0) do {                                                       \
    __builtin_amdgcn_s_setprio(1);                                            \
    _Pragma("unroll")                                                         \
    for (int i = 0; i < 4; ++i)                                               \
      _Pragma("unroll")                                                       \
      for (int j = 0; j < 4; ++j)                                             \
        acc[(i0) + i][j] = __builtin_amdgcn_mfma_f32_16x16x32_bf16(           \
            afr[i], bfr[j], acc[(i0) + i][j], 0, 0, 0);                       \
    __builtin_amdgcn_s_setprio(0);                                            \
  } while (0)

#define BAR() do {                                                            \
    __builtin_amdgcn_sched_barrier(0);                                        \
    asm volatile("" ::: "memory");                                            \
    __builtin_amdgcn_s_barrier();                                             \
    asm volatile("" ::: "memory");                                            \
    __builtin_amdgcn_sched_barrier(0);                                        \
  } while (0)

template <int EPI>
__global__ __launch_bounds__(512, 2) void gemm256_kernel(
    const unsigned short* __restrict__ A,
    const unsigned short* __restrict__ Bt,
    void* __restrict__ Cout,
    int M, int N, int K,
    const float* __restrict__ skip_in,
    const float* __restrict__ skip_w)
{
  __shared__ __align__(16) unsigned short As[4][256 * 32];
  __shared__ __align__(16) unsigned short Bs[4][256 * 32];

  const int tid  = threadIdx.x;
  const int lane = tid & 63;
  const int wave = tid >> 6;   // 0..7
  const int wm = wave >> 2;    // 0..1 (m half)
  const int wn = wave & 3;     // 0..3 (n quarter)

  // XCD-compact tile assignment (M/256 == 64 for both GEMMs: 8 XCDs x 8 m-tiles)
  const int flat    = blockIdx.x;
  const int xcd     = flat & 7;
  const int local   = flat >> 3;
  const int m_tile  = xcd * 8 + (local & 7);
  const int n_tile  = local >> 3;
  const int m0 = m_tile * 256;
  const int n0 = n_tile * 256;

  const int ldr = lane >> 2;   // 0..15: row within a 16-row staging group
  const int pos = lane & 3;    // 16B chunk position within the 64B row
  const int lm  = lane & 15;   // fragment row (A: m, B: n)
  const int q   = lane >> 4;   // fragment k-chunk (k = q*8 + j)

  // Per-thread staging geometry (two rows per thread; 8 waves x 32 rows = 256)
  const int r0 = wave * 32 + ldr;
  const int r1 = r0 + 16;
  const int ca0 = pos ^ ((r0 >> 1) & 3);
  const int ca1 = pos ^ ((r1 >> 1) & 3);

  const unsigned short* gA0 = A  + (size_t)(m0 + r0) * K + ca0 * 8;
  const unsigned short* gA1 = A  + (size_t)(m0 + r1) * K + ca1 * 8;
  const unsigned short* gB0 = Bt + (size_t)(n0 + r0) * K + ca0 * 8;
  const unsigned short* gB1 = Bt + (size_t)(n0 + r1) * K + ca1 * 8;
  const int lofs0 = r0 * 32 + pos * 8;
  const int lofs1 = r1 * 32 + pos * 8;

  floatx4 acc[8][4];
#pragma unroll
  for (int i = 0; i < 8; ++i)
#pragma unroll
    for (int j = 0; j < 4; ++j)
      acc[i][j] = (floatx4){0.f, 0.f, 0.f, 0.f};

  const int KT = K >> 5;   // 32 or 64 K-tiles; KT >= 4 assumed

  // Prologue: prefetch tiles 0..2 into ring slots 0..2 (12 loads/thread),
  // wait for tile 0 only (8 loads = tiles 1,2 stay in flight).
  STAGE(0, 0);
  STAGE(1, 1);
  STAGE(2, 2);
  asm volatile("s_waitcnt vmcnt(8)" ::: "memory");
  __builtin_amdgcn_s_barrier();
  asm volatile("" ::: "memory");

  // Steady state: two paced phases per K-tile; tile kt+3 staged A-pair in
  // phase A, B-pair in phase B; vmcnt(8) checkpoint once per K-tile keeps
  // tiles kt+2,kt+3 in flight across the barrier.
  for (int kt = 0; kt + 3 < KT; ++kt) {
    const int cur = kt & 3;
    const int b3  = (kt + 3) & 3;
    const int ko3 = (kt + 3) * 32;
    bf16x8 afr[4], bfr[4];

    // ---- phase A ----
    READ_B(cur);
    READ_A(cur, 0);
    GLDS(gA0 + ko3, &As[b3][lofs0]);
    GLDS(gA1 + ko3, &As[b3][lofs1]);
    BAR();
    MFMA16(0);
    BAR();

    // ---- phase B ----
    READ_A(cur, 4);
    GLDS(gB0 + ko3, &Bs[b3][lofs0]);
    GLDS(gB1 + ko3, &Bs[b3][lofs1]);
    asm volatile("s_waitcnt vmcnt(8)" ::: "memory");
    BAR();
    MFMA16(4);
    BAR();
  }

  // Tail: tiles KT-3, KT-2, KT-1 (no staging left).
  {
    const int cur = (KT - 3) & 3;
    bf16x8 afr[4], bfr[4];
    READ_B(cur);
    READ_A(cur, 0);
    BAR();
    MFMA16(0);
    BAR();
    READ_A(cur, 4);
    asm volatile("s_waitcnt vmcnt(4)" ::: "memory");  // tile KT-2 landed
    BAR();
    MFMA16(4);
    BAR();
  }
  {
    const int cur = (KT - 2) & 3;
    bf16x8 afr[4], bfr[4];
    READ_B(cur);
    READ_A(cur, 0);
    BAR();
    MFMA16(0);
    BAR();
    READ_A(cur, 4);
    asm volatile("s_waitcnt vmcnt(0)" ::: "memory");  // tile KT-1 landed
    BAR();
    MFMA16(4);
    BAR();
  }
  {
    const int cur = (KT - 1) & 3;
    bf16x8 afr[4], bfr[4];
    READ_B(cur);
    READ_A(cur, 0);
    MFMA16(0);
    READ_A(cur, 4);
    MFMA16(4);
  }

  // Epilogue. C/D layout: col = lane&15, row = (lane>>4)*4 + reg.
#pragma unroll
  for (int i = 0; i < 8; ++i) {
#pragma unroll
    for (int j = 0; j < 4; ++j) {
      const int row0 = m0 + wm * 128 + i * 16 + q * 4;
      const int col  = n0 + wn * 64 + j * 16 + lm;
#pragma unroll
      for (int r = 0; r < 4; ++r) {
        const size_t idx = (size_t)(row0 + r) * N + col;
        if (EPI == 0) {
          ((unsigned short*)Cout)[idx] = f2bf(acc[i][j][r]);
        } else {
          ((float*)Cout)[idx] = acc[i][j][r] + skip_in[idx] * skip_w[col];
        }
      }
    }
  }
}

// ---------------- chunked scan over T ----------------
// Bu layout: [(b*4096 + t) * 2048 + h] re-plane (h<1024), +1024 im-plane.
// tid = b*32768 + c*1024 + h  (B=4, C=32 chunks of L=128, H=1024)

__global__ void scan_finals(const unsigned short* __restrict__ Bu,
                            const float* __restrict__ lam,
                            float2* __restrict__ finals)
{
  int tid = blockIdx.x * 256 + threadIdx.x;
  int h = tid & 1023, c = (tid >> 10) & 31, b = tid >> 15;
  float lre = lam[h], lim = lam[1024 + h];
  const unsigned short* p = Bu + ((size_t)(b * 4096 + c * 128) * 2048) + h;
  float yre = 0.f, yim = 0.f;
#pragma unroll 4
  for (int t = 0; t < 128; ++t) {
    float ure = bf2f(p[0]);
    float uim = bf2f(p[1024]);
    float nre = fmaf(lre, yre, fmaf(-lim, yim, ure));
    float nim = fmaf(lre, yim, fmaf(lim, yre, uim));
    yre = nre; yim = nim;
    p += 2048;
  }
  finals[tid] = make_float2(yre, yim);
}

__global__ void scan_carries(const float2* __restrict__ finals,
                             const float* __restrict__ lamL,
                             float2* __restrict__ carry)
{
  int tid = blockIdx.x * 256 + threadIdx.x;  // 4096 = B*H
  int h = tid & 1023, b = tid >> 10;
  float Lre = lamL[h], Lim = lamL[1024 + h];
  float Hre = 0.f, Him = 0.f;
  for (int c = 0; c < 32; ++c) {
    size_t i = ((size_t)(b * 32 + c) << 10) + h;
    carry[i] = make_float2(Hre, Him);   // carry INTO chunk c (H_{c-1})
    float2 f = finals[i];
    float nre = fmaf(Lre, Hre, fmaf(-Lim, Him, f.x));
    float nim = fmaf(Lre, Him, fmaf(Lim, Hre, f.y));
    Hre = nre; Him = nim;
  }
}

__global__ void scan_apply(const float* __restrict__ lam,
                           const float2* __restrict__ carry,
                           unsigned short* __restrict__ Bu)  // in-place -> hs
{
  int tid = blockIdx.x * 256 + threadIdx.x;
  int h = tid & 1023, c = (tid >> 10) & 31, b = tid >> 15;
  float lre = lam[h], lim = lam[1024 + h];
  float2 cv = carry[tid];
  float yre = cv.x, yim = cv.y;
  unsigned short* p = Bu + ((size_t)(b * 4096 + c * 128) * 2048) + h;
#pragma unroll 4
  for (int t = 0; t < 128; ++t) {
    float ure = bf2f(p[0]);
    float uim = bf2f(p[1024]);
    float nre = fmaf(lre, yre, fmaf(-lim, yim, ure));
    float nim = fmaf(lre, yim, fmaf(lim, yre, uim));
    yre = nre; yim = nim;
    p[0]    = f2bf(yre);
    p[1024] = f2bf(yim);
    p += 2048;
  }
}

// ---------------- launch ----------------

extern "C" void kernel_launch(void* const* d_in, const int* in_sizes, int n_in,
                              void* d_out, int out_size, void* d_ws, size_t ws_size,
                              hipStream_t stream)
{
  const float* inputs    = (const float*)d_in[0];
  const float* nu_log    = (const float*)d_in[1];
  const float* theta_log = (const float*)d_in[2];
  const float* B_re      = (const float*)d_in[3];
  const float* B_im      = (const float*)d_in[4];
  const float* C_re      = (const float*)d_in[5];
  const float* C_im      = (const float*)d_in[6];
  const float* D_skip    = (const float*)d_in[7];
  float* out = (float*)d_out;

  char* ws = (char*)d_ws;
  float* lam   = (float*)ws;            // 2048 f32
  float* lamL  = lam + 2048;            // 2048 f32
  float* gamma = lamL + 2048;           // 1024 f32
  unsigned short* inp_bf = (unsigned short*)(ws + (1 << 16));       // 16384x1024 bf16
  unsigned short* Bcat   = inp_bf + (size_t)16384 * 1024;           // 2048x1024
  unsigned short* Ccat   = Bcat   + (size_t)2048 * 1024;            // 1024x2048
  unsigned short* Bu     = Ccat   + (size_t)1024 * 2048;            // 16384x2048 (re|im), becomes hs in place
  float2* finals = (float2*)(Bu + (size_t)16384 * 2048);            // 131072
  float2* carry  = finals + 131072;                                 // 131072
  // total ws use ~111 MB

  prep_params<<<4,    256, 0, stream>>>(nu_log, theta_log, lam, lamL, gamma);
  prep_B     <<<8192, 256, 0, stream>>>(B_re, B_im, gamma, Bcat);
  prep_C     <<<8192, 256, 0, stream>>>(C_re, C_im, Ccat);
  conv_inputs<<<16384,256, 0, stream>>>(inputs, inp_bf);

  // GEMM1: Bu[bt, n] = inputs @ Bcat^T   (M=16384, N=2048, K=1024) -> 64x8 tiles
  gemm256_kernel<0><<<512, 512, 0, stream>>>(
      inp_bf, Bcat, Bu, 16384, 2048, 1024, nullptr, nullptr);

  scan_finals <<<512, 256, 0, stream>>>(Bu, lam, finals);
  scan_carries<<<16,  256, 0, stream>>>(finals, lamL, carry);
  scan_apply  <<<512, 256, 0, stream>>>(lam, carry, Bu);   // Bu -> hs in place

  // GEMM2: out[bt, d] = hs @ Ccat^T + inputs * D_skip  (M=16384, N=1024, K=2048) -> 64x4 tiles
  gemm256_kernel<1><<<256, 512, 0, stream>>>(
      Bu, Ccat, out, 16384, 1024, 2048, inputs, D_skip);
}